// Round 9
// baseline (218.747 us; speedup 1.0000x reference)
//
#include <hip/hip_runtime.h>

#define NN 100000
#define NE 1600000
#define D 64
#define NXCD 8

#define BKT 256                          // row buckets
#define BROWS ((NN + BKT - 1) / BKT)     // 391 rows per bucket (fits 9 bits)
#define CAP 8192                         // slots per bucket (mean 6250, sigma 79)
#define P1_NB 512                        // pass-1 blocks
#define P1_T 1024                        // pass-1 threads per block
#define EPB ((NE + P1_NB - 1) / P1_NB)   // 3125 edges per pass-1 block

typedef unsigned short u16;
typedef unsigned int u32;

// ---------------- bf16 helpers (bit-level, RNE) ----------------

__device__ __forceinline__ float bf2f(u16 u) {
    union { u32 i; float f; } x; x.i = ((u32)u) << 16; return x.f;
}
__device__ __forceinline__ u16 f2bf(float f) {
    union { float f; u32 i; } x; x.f = f;
    u32 r = x.i + 0x7FFF + ((x.i >> 16) & 1);   // round-to-nearest-even
    return (u16)(r >> 16);
}

__device__ __forceinline__ unsigned xcc_id() {
    unsigned v;
    asm volatile("s_getreg_b32 %0, hwreg(HW_REG_XCC_ID)" : "=s"(v));
    return v & (NXCD - 1);
}

__global__ void softmax_kernel(const float* __restrict__ hw, float* __restrict__ wsm) {
    float m = fmaxf(fmaxf(hw[0], hw[1]), hw[2]);
    float e0 = expf(hw[0] - m), e1 = expf(hw[1] - m), e2 = expf(hw[2] - m);
    float s = e0 + e1 + e2;
    wsm[0] = e0 / s; wsm[1] = e1 / s; wsm[2] = e2 / s;
}

// Standalone per-XCD col-degree histogram, full occupancy (8 blocks/CU).
__global__ void hist8_kernel(const int* __restrict__ col, int* __restrict__ cnt8) {
    unsigned k = xcc_id();
    int* degc = cnt8 + (size_t)k * NN;
    int e = blockIdx.x * blockDim.x + threadIdx.x;
    if (e < NE)
        __hip_atomic_fetch_add(&degc[col[e]], 1, __ATOMIC_RELAXED, __HIP_MEMORY_SCOPE_WORKGROUP);
}

// ---------------- fused pass 1: stage edges in LDS, histogram, reserve, scatter ---
__global__ void __launch_bounds__(P1_T) fused_p1(const int* __restrict__ row,
                                                 const int* __restrict__ col,
                                                 int* __restrict__ bcnt,
                                                 u32* __restrict__ buck) {
    __shared__ int lds_r[EPB];
    __shared__ int lds_c[EPB];
    __shared__ int h[BKT];
    int t = threadIdx.x;
    int beg = blockIdx.x * EPB, end = min(NE, beg + EPB);
    int n = end - beg;
    for (int i = t; i < BKT; i += P1_T) h[i] = 0;
    __syncthreads();
    // stage + row-bucket histogram
    for (int i = t; i < n; i += P1_T) {
        int r = row[beg + i], c = col[beg + i];
        lds_r[i] = r; lds_c[i] = c;
        atomicAdd(&h[r / BROWS], 1);
    }
    __syncthreads();
    // reserve space in each bucket
    for (int b = t; b < BKT; b += P1_T) {
        int cl = h[b];
        h[b] = atomicAdd(&bcnt[b], cl);   // h[b] now = this block's base cursor
    }
    __syncthreads();
    // scatter packed (rloc<<17 | col)
    for (int i = t; i < n; i += P1_T) {
        int r = lds_r[i], c = lds_c[i];
        int b = r / BROWS;
        int pos = atomicAdd(&h[b], 1);    // LDS atomic
        buck[(size_t)b * CAP + pos] = ((u32)(r - b * BROWS) << 17) | (u32)c;
    }
}

// Sum the 8 degree copies -> dis = rsqrt(deg+1), dsi = sqrt(deg+1).
__global__ void reduce8_kernel(const int* __restrict__ cnt8,
                               float* __restrict__ dis, float* __restrict__ dsi) {
    int i = blockIdx.x * blockDim.x + threadIdx.x;
    if (i >= NN) return;
    int dsum = 0;
    #pragma unroll
    for (int k = 0; k < NXCD; ++k) dsum += cnt8[(size_t)k * NN + i];
    float dg = (float)(dsum + 1);          // +1 self loop, always > 0
    dis[i] = rsqrtf(dg);
    dsi[i] = sqrtf(dg);
}

// y1 = bf16( dis (x) x )
__global__ void scale_kernel(const float4* __restrict__ x, const float* __restrict__ dis,
                             ushort4* __restrict__ y1) {
    int idx = blockIdx.x * blockDim.x + threadIdx.x; // over NN*16
    if (idx >= NN * (D / 4)) return;
    float s = dis[idx >> 4];
    float4 v = x[idx];
    ushort4 o;
    o.x = f2bf(s * v.x); o.y = f2bf(s * v.y); o.z = f2bf(s * v.z); o.w = f2bf(s * v.w);
    y1[idx] = o;
}

// Exclusive scan of the 256 bucket counts.
__global__ void bscan_kernel(const int* __restrict__ bcnt, int* __restrict__ scanb) {
    __shared__ int s[BKT];
    int t = threadIdx.x;
    int v = bcnt[t];
    s[t] = v;
    __syncthreads();
    for (int st = 1; st < BKT; st <<= 1) {
        int u = (t >= st) ? s[t - st] : 0;
        __syncthreads();
        s[t] += u;
        __syncthreads();
    }
    scanb[t] = s[t] - v;
    if (t == BKT - 1) scanb[BKT] = s[t];
}

// Pass 2: one block per bucket — LDS row-count, LDS scan -> rowptr, local scatter -> adjc.
__global__ void __launch_bounds__(1024) p2_build(const int* __restrict__ scanb,
                                                 const u32* __restrict__ buck,
                                                 int* __restrict__ adjc,
                                                 int* __restrict__ rowptr) {
    __shared__ int ca[BROWS];
    __shared__ int sums[1024];
    int b = blockIdx.x, t = threadIdx.x;
    int row0 = b * BROWS;
    int nrows = min(BROWS, NN - row0);
    int ebeg = scanb[b];
    int cntb = scanb[b + 1] - ebeg;
    const u32* eb = buck + (size_t)b * CAP;

    for (int i = t; i < nrows; i += 1024) ca[i] = 0;
    __syncthreads();
    for (int e = t; e < cntb; e += 1024)
        atomicAdd(&ca[eb[e] >> 17], 1);
    __syncthreads();
    int v = (t < nrows) ? ca[t] : 0;
    sums[t] = v;
    __syncthreads();
    for (int st = 1; st < 1024; st <<= 1) {
        int u = (t >= st) ? sums[t - st] : 0;
        __syncthreads();
        sums[t] += u;
        __syncthreads();
    }
    int excl = sums[t] - v;
    if (t < nrows) {
        rowptr[row0 + t] = ebeg + excl;
        ca[t] = ebeg + excl;
    }
    if (b == 0 && t == 0) rowptr[NN] = NE;
    __syncthreads();
    for (int e = t; e < cntb; e += 1024) {
        u32 p = eb[e];
        int pos = atomicAdd(&ca[p >> 17], 1); // LDS atomic
        adjc[pos] = (int)(p & 0x1FFFFu);
    }
}

// ---------------- propagate kernels (gather, no atomics) ----------------
// One wave per node. 4 subgroups of 16 lanes: subgroup sg handles edge slot sg,
// lane covers feature quad fq = (l&15) as ushort4 (8B). 16 line requests/batch.

__global__ void prop1_kernel(const int* __restrict__ rowptr,
                             const int* __restrict__ adjc,
                             const float* __restrict__ dis,
                             const u16* __restrict__ y1,
                             u16* __restrict__ y2) {
    int t = blockIdx.x * blockDim.x + threadIdx.x;
    int n = t >> 6, l = t & 63;
    if (n >= NN) return;
    int sg = l >> 4, fq = l & 15;
    int beg = rowptr[n], end = rowptr[n + 1];
    float a0 = 0.f, a1 = 0.f, a2 = 0.f, a3 = 0.f;
    int j = beg;
    for (; j + 16 <= end; j += 16) {
        #pragma unroll
        for (int u = 0; u < 4; ++u) {
            int c = adjc[j + u * 4 + sg];
            ushort4 v = *(const ushort4*)&y1[c * D + fq * 4];
            a0 += bf2f(v.x); a1 += bf2f(v.y); a2 += bf2f(v.z); a3 += bf2f(v.w);
        }
    }
    for (; j + 4 <= end; j += 4) {
        int c = adjc[j + sg];
        ushort4 v = *(const ushort4*)&y1[c * D + fq * 4];
        a0 += bf2f(v.x); a1 += bf2f(v.y); a2 += bf2f(v.z); a3 += bf2f(v.w);
    }
    if (sg < end - j) {
        int c = adjc[j + sg];
        ushort4 v = *(const ushort4*)&y1[c * D + fq * 4];
        a0 += bf2f(v.x); a1 += bf2f(v.y); a2 += bf2f(v.z); a3 += bf2f(v.w);
    }
    a0 += __shfl_xor(a0, 16); a0 += __shfl_xor(a0, 32);
    a1 += __shfl_xor(a1, 16); a1 += __shfl_xor(a1, 32);
    a2 += __shfl_xor(a2, 16); a2 += __shfl_xor(a2, 32);
    a3 += __shfl_xor(a3, 16); a3 += __shfl_xor(a3, 32);
    if (l < 16) {
        ushort4 s = *(const ushort4*)&y1[n * D + l * 4];   // self loop
        a0 += bf2f(s.x); a1 += bf2f(s.y); a2 += bf2f(s.z); a3 += bf2f(s.w);
        float di = dis[n], d2 = di * di;
        ushort4 o;
        o.x = f2bf(d2 * a0); o.y = f2bf(d2 * a1); o.z = f2bf(d2 * a2); o.w = f2bf(d2 * a3);
        *(ushort4*)&y2[n * D + l * 4] = o;
    }
}

// out = w0*x + w1*(dsi*y2[n]) + w2*di*(y2[n] + sum_c y2[c])
__global__ void prop2_kernel(const float* __restrict__ x,
                             const int* __restrict__ rowptr,
                             const int* __restrict__ adjc,
                             const float* __restrict__ dis,
                             const float* __restrict__ dsi,
                             const u16* __restrict__ y2,
                             const float* __restrict__ wsm,
                             float* __restrict__ out) {
    int t = blockIdx.x * blockDim.x + threadIdx.x;
    int n = t >> 6, l = t & 63;
    if (n >= NN) return;
    int sg = l >> 4, fq = l & 15;
    int beg = rowptr[n], end = rowptr[n + 1];
    float a0 = 0.f, a1 = 0.f, a2 = 0.f, a3 = 0.f;
    int j = beg;
    for (; j + 16 <= end; j += 16) {
        #pragma unroll
        for (int u = 0; u < 4; ++u) {
            int c = adjc[j + u * 4 + sg];
            ushort4 v = *(const ushort4*)&y2[c * D + fq * 4];
            a0 += bf2f(v.x); a1 += bf2f(v.y); a2 += bf2f(v.z); a3 += bf2f(v.w);
        }
    }
    for (; j + 4 <= end; j += 4) {
        int c = adjc[j + sg];
        ushort4 v = *(const ushort4*)&y2[c * D + fq * 4];
        a0 += bf2f(v.x); a1 += bf2f(v.y); a2 += bf2f(v.z); a3 += bf2f(v.w);
    }
    if (sg < end - j) {
        int c = adjc[j + sg];
        ushort4 v = *(const ushort4*)&y2[c * D + fq * 4];
        a0 += bf2f(v.x); a1 += bf2f(v.y); a2 += bf2f(v.z); a3 += bf2f(v.w);
    }
    a0 += __shfl_xor(a0, 16); a0 += __shfl_xor(a0, 32);
    a1 += __shfl_xor(a1, 16); a1 += __shfl_xor(a1, 32);
    a2 += __shfl_xor(a2, 16); a2 += __shfl_xor(a2, 32);
    a3 += __shfl_xor(a3, 16); a3 += __shfl_xor(a3, 32);
    if (l < 16) {
        ushort4 s = *(const ushort4*)&y2[n * D + l * 4];
        float y0 = bf2f(s.x), y1v = bf2f(s.y), y2v = bf2f(s.z), y3 = bf2f(s.w);
        a0 += y0; a1 += y1v; a2 += y2v; a3 += y3;   // self loop in hop-2 sum
        float di = dis[n], ds = dsi[n];
        float w0 = wsm[0], w1 = wsm[1], w2 = wsm[2];
        float4 xv = *(const float4*)&x[n * D + l * 4];
        float4 o;
        o.x = w0 * xv.x + w1 * (ds * y0) + w2 * (di * a0);
        o.y = w0 * xv.y + w1 * (ds * y1v) + w2 * (di * a1);
        o.z = w0 * xv.z + w1 * (ds * y2v) + w2 * (di * a2);
        o.w = w0 * xv.w + w1 * (ds * y3) + w2 * (di * a3);
        *(float4*)&out[n * D + l * 4] = o;
    }
}

// ---------------- launch ----------------

extern "C" void kernel_launch(void* const* d_in, const int* in_sizes, int n_in,
                              void* d_out, int out_size, void* d_ws, size_t ws_size,
                              hipStream_t stream) {
    const float* x   = (const float*)d_in[0];
    const int*   ei  = (const int*)d_in[1];   // [2, NE]
    const float* hw  = (const float*)d_in[2]; // [3]
    float*       out = (float*)d_out;

    const int* row = ei;       // scatter destination
    const int* col = ei + NE;  // gather source

    char* ws = (char*)d_ws;
    size_t off = 0;
    auto alloc = [&](size_t bytes) { size_t p = off; off += (bytes + 255) & ~(size_t)255; return p; };
    float* wsm    = (float*)(ws + alloc(16));
    int*   cnt8   = (int*)  (ws + alloc((size_t)NXCD * NN * 4));
    int*   bcnt   = (int*)  (ws + alloc((size_t)BKT * 4));
    int*   scanb  = (int*)  (ws + alloc((size_t)(BKT + 1) * 4));
    float* dis    = (float*)(ws + alloc((size_t)NN * 4));
    float* dsi    = (float*)(ws + alloc((size_t)NN * 4));
    u32*   buck   = (u32*)  (ws + alloc((size_t)BKT * CAP * 4));
    int*   adjc   = (int*)  (ws + alloc((size_t)NE * 4));
    int*   rowptr = (int*)  (ws + alloc((size_t)(NN + 1) * 4));
    u16*   y1     = (u16*)  (ws + alloc((size_t)NN * D * 2));
    u16*   y2     = (u16*)  (ws + alloc((size_t)NN * D * 2));

    hipMemsetAsync(cnt8, 0, (size_t)NXCD * NN * 4, stream);
    hipMemsetAsync(bcnt, 0, (size_t)BKT * 4, stream);

    hist8_kernel<<<(NE + 255) / 256, 256, 0, stream>>>(col, cnt8);
    fused_p1<<<P1_NB, P1_T, 0, stream>>>(row, col, bcnt, buck);
    reduce8_kernel<<<(NN + 255) / 256, 256, 0, stream>>>(cnt8, dis, dsi);
    softmax_kernel<<<1, 1, 0, stream>>>(hw, wsm);
    scale_kernel<<<(NN * (D / 4) + 255) / 256, 256, 0, stream>>>((const float4*)x, dis, (ushort4*)y1);
    bscan_kernel<<<1, BKT, 0, stream>>>(bcnt, scanb);
    p2_build<<<BKT, 1024, 0, stream>>>(scanb, buck, adjc, rowptr);

    const int prop_blocks = (NN * 64 + 255) / 256; // 25000
    prop1_kernel<<<prop_blocks, 256, 0, stream>>>(rowptr, adjc, dis, y1, y2);
    prop2_kernel<<<prop_blocks, 256, 0, stream>>>(x, rowptr, adjc, dis, dsi, y2, wsm, out);
}

// Round 10
// 164.976 us; speedup vs baseline: 1.3259x; 1.3259x over previous
//
#include <hip/hip_runtime.h>

#define NN 100000
#define NE 1600000
#define D 64

#define BKT 256                          // buckets (both row- and col-space)
#define BROWS ((NN + BKT - 1) / BKT)     // 391 per bucket (fits 9 bits)
#define CAP 8192                         // slots per bucket (mean 6250, sigma 79)
#define P1_NB 512                        // pass-1 blocks
#define P1_T 1024                        // pass-1 threads per block
#define EPB ((NE + P1_NB - 1) / P1_NB)   // 3125 edges per pass-1 block

typedef unsigned short u16;
typedef unsigned int u32;

// ---------------- bf16 helpers (bit-level, RNE) ----------------

__device__ __forceinline__ float bf2f(u16 u) {
    union { u32 i; float f; } x; x.i = ((u32)u) << 16; return x.f;
}
__device__ __forceinline__ u16 f2bf(float f) {
    union { float f; u32 i; } x; x.f = f;
    u32 r = x.i + 0x7FFF + ((x.i >> 16) & 1);   // round-to-nearest-even
    return (u16)(r >> 16);
}

__global__ void softmax_kernel(const float* __restrict__ hw, float* __restrict__ wsm) {
    float m = fmaxf(fmaxf(hw[0], hw[1]), hw[2]);
    float e0 = expf(hw[0] - m), e1 = expf(hw[1] - m), e2 = expf(hw[2] - m);
    float s = e0 + e1 + e2;
    wsm[0] = e0 / s; wsm[1] = e1 / s; wsm[2] = e2 / s;
}

// ---------------- fused pass 1: stage, double-bucket (row & col), scatter ----
// Row side: packed (rloc<<17 | col) u32 for CSR build.
// Col side: 9-bit col-remainder u16 for the degree count (replaces all global
// histogram atomics — LDS only).
__global__ void __launch_bounds__(P1_T) fused_p1(const int* __restrict__ row,
                                                 const int* __restrict__ col,
                                                 int* __restrict__ bcnt,
                                                 int* __restrict__ bcnt2,
                                                 u32* __restrict__ buck,
                                                 u16* __restrict__ buck2) {
    __shared__ int lds_r[EPB];
    __shared__ int lds_c[EPB];
    __shared__ int h[BKT];
    __shared__ int h2[BKT];
    int t = threadIdx.x;
    int beg = blockIdx.x * EPB, end = min(NE, beg + EPB);
    int n = end - beg;
    for (int i = t; i < BKT; i += P1_T) { h[i] = 0; h2[i] = 0; }
    __syncthreads();
    // stage + both bucket histograms
    for (int i = t; i < n; i += P1_T) {
        int r = row[beg + i], c = col[beg + i];
        lds_r[i] = r; lds_c[i] = c;
        atomicAdd(&h[r / BROWS], 1);
        atomicAdd(&h2[c / BROWS], 1);
    }
    __syncthreads();
    // reserve space in each bucket
    for (int b = t; b < BKT; b += P1_T) {
        int cl = h[b];
        h[b] = atomicAdd(&bcnt[b], cl);    // base cursor (row side)
        int cl2 = h2[b];
        h2[b] = atomicAdd(&bcnt2[b], cl2); // base cursor (col side)
    }
    __syncthreads();
    // scatter
    for (int i = t; i < n; i += P1_T) {
        int r = lds_r[i], c = lds_c[i];
        int b = r / BROWS;
        int pos = atomicAdd(&h[b], 1);     // LDS atomic
        buck[(size_t)b * CAP + pos] = ((u32)(r - b * BROWS) << 17) | (u32)c;
        int b2 = c / BROWS;
        int pos2 = atomicAdd(&h2[b2], 1);  // LDS atomic
        buck2[(size_t)b2 * CAP + pos2] = (u16)(c - b2 * BROWS);
    }
}

// Degree count from col-bucketed u16 remainders -> dis = rsqrt(deg+1), dsi = sqrt.
__global__ void __launch_bounds__(1024) deg_count(const int* __restrict__ bcnt2,
                                                  const u16* __restrict__ buck2,
                                                  float* __restrict__ dis,
                                                  float* __restrict__ dsi) {
    __shared__ int ca[BROWS];
    int b = blockIdx.x, t = threadIdx.x;
    int row0 = b * BROWS;
    int nrows = min(BROWS, NN - row0);
    int cntb = bcnt2[b];
    const u16* eb = buck2 + (size_t)b * CAP;
    for (int i = t; i < nrows; i += 1024) ca[i] = 0;
    __syncthreads();
    for (int e = t; e < cntb; e += 1024)
        atomicAdd(&ca[eb[e]], 1);          // LDS atomic
    __syncthreads();
    if (t < nrows) {
        float dg = (float)(ca[t] + 1);     // +1 self loop, always > 0
        dis[row0 + t] = rsqrtf(dg);
        dsi[row0 + t] = sqrtf(dg);
    }
}

// y1 = bf16( dis (x) x )
__global__ void scale_kernel(const float4* __restrict__ x, const float* __restrict__ dis,
                             ushort4* __restrict__ y1) {
    int idx = blockIdx.x * blockDim.x + threadIdx.x; // over NN*16
    if (idx >= NN * (D / 4)) return;
    float s = dis[idx >> 4];
    float4 v = x[idx];
    ushort4 o;
    o.x = f2bf(s * v.x); o.y = f2bf(s * v.y); o.z = f2bf(s * v.z); o.w = f2bf(s * v.w);
    y1[idx] = o;
}

// Exclusive scan of the 256 row-bucket counts.
__global__ void bscan_kernel(const int* __restrict__ bcnt, int* __restrict__ scanb) {
    __shared__ int s[BKT];
    int t = threadIdx.x;
    int v = bcnt[t];
    s[t] = v;
    __syncthreads();
    for (int st = 1; st < BKT; st <<= 1) {
        int u = (t >= st) ? s[t - st] : 0;
        __syncthreads();
        s[t] += u;
        __syncthreads();
    }
    scanb[t] = s[t] - v;
    if (t == BKT - 1) scanb[BKT] = s[t];
}

// Pass 2: one block per bucket — LDS row-count, LDS scan -> rowptr, local scatter -> adjc.
__global__ void __launch_bounds__(1024) p2_build(const int* __restrict__ scanb,
                                                 const u32* __restrict__ buck,
                                                 int* __restrict__ adjc,
                                                 int* __restrict__ rowptr) {
    __shared__ int ca[BROWS];
    __shared__ int sums[1024];
    int b = blockIdx.x, t = threadIdx.x;
    int row0 = b * BROWS;
    int nrows = min(BROWS, NN - row0);
    int ebeg = scanb[b];
    int cntb = scanb[b + 1] - ebeg;
    const u32* eb = buck + (size_t)b * CAP;

    for (int i = t; i < nrows; i += 1024) ca[i] = 0;
    __syncthreads();
    for (int e = t; e < cntb; e += 1024)
        atomicAdd(&ca[eb[e] >> 17], 1);
    __syncthreads();
    int v = (t < nrows) ? ca[t] : 0;
    sums[t] = v;
    __syncthreads();
    for (int st = 1; st < 1024; st <<= 1) {
        int u = (t >= st) ? sums[t - st] : 0;
        __syncthreads();
        sums[t] += u;
        __syncthreads();
    }
    int excl = sums[t] - v;
    if (t < nrows) {
        rowptr[row0 + t] = ebeg + excl;
        ca[t] = ebeg + excl;
    }
    if (b == 0 && t == 0) rowptr[NN] = NE;
    __syncthreads();
    for (int e = t; e < cntb; e += 1024) {
        u32 p = eb[e];
        int pos = atomicAdd(&ca[p >> 17], 1); // LDS atomic
        adjc[pos] = (int)(p & 0x1FFFFu);
    }
}

// ---------------- propagate kernels (gather, no atomics) ----------------
// One wave per node. 4 subgroups of 16 lanes: subgroup sg handles edge slot sg,
// lane covers feature quad fq = (l&15) as ushort4 (8B). 16 line requests/batch.

__global__ void prop1_kernel(const int* __restrict__ rowptr,
                             const int* __restrict__ adjc,
                             const float* __restrict__ dis,
                             const u16* __restrict__ y1,
                             u16* __restrict__ y2) {
    int t = blockIdx.x * blockDim.x + threadIdx.x;
    int n = t >> 6, l = t & 63;
    if (n >= NN) return;
    int sg = l >> 4, fq = l & 15;
    int beg = rowptr[n], end = rowptr[n + 1];
    float a0 = 0.f, a1 = 0.f, a2 = 0.f, a3 = 0.f;
    int j = beg;
    for (; j + 16 <= end; j += 16) {
        #pragma unroll
        for (int u = 0; u < 4; ++u) {
            int c = adjc[j + u * 4 + sg];
            ushort4 v = *(const ushort4*)&y1[c * D + fq * 4];
            a0 += bf2f(v.x); a1 += bf2f(v.y); a2 += bf2f(v.z); a3 += bf2f(v.w);
        }
    }
    for (; j + 4 <= end; j += 4) {
        int c = adjc[j + sg];
        ushort4 v = *(const ushort4*)&y1[c * D + fq * 4];
        a0 += bf2f(v.x); a1 += bf2f(v.y); a2 += bf2f(v.z); a3 += bf2f(v.w);
    }
    if (sg < end - j) {
        int c = adjc[j + sg];
        ushort4 v = *(const ushort4*)&y1[c * D + fq * 4];
        a0 += bf2f(v.x); a1 += bf2f(v.y); a2 += bf2f(v.z); a3 += bf2f(v.w);
    }
    a0 += __shfl_xor(a0, 16); a0 += __shfl_xor(a0, 32);
    a1 += __shfl_xor(a1, 16); a1 += __shfl_xor(a1, 32);
    a2 += __shfl_xor(a2, 16); a2 += __shfl_xor(a2, 32);
    a3 += __shfl_xor(a3, 16); a3 += __shfl_xor(a3, 32);
    if (l < 16) {
        ushort4 s = *(const ushort4*)&y1[n * D + l * 4];   // self loop
        a0 += bf2f(s.x); a1 += bf2f(s.y); a2 += bf2f(s.z); a3 += bf2f(s.w);
        float di = dis[n], d2 = di * di;
        ushort4 o;
        o.x = f2bf(d2 * a0); o.y = f2bf(d2 * a1); o.z = f2bf(d2 * a2); o.w = f2bf(d2 * a3);
        *(ushort4*)&y2[n * D + l * 4] = o;
    }
}

// out = w0*x + w1*(dsi*y2[n]) + w2*di*(y2[n] + sum_c y2[c])
__global__ void prop2_kernel(const float* __restrict__ x,
                             const int* __restrict__ rowptr,
                             const int* __restrict__ adjc,
                             const float* __restrict__ dis,
                             const float* __restrict__ dsi,
                             const u16* __restrict__ y2,
                             const float* __restrict__ wsm,
                             float* __restrict__ out) {
    int t = blockIdx.x * blockDim.x + threadIdx.x;
    int n = t >> 6, l = t & 63;
    if (n >= NN) return;
    int sg = l >> 4, fq = l & 15;
    int beg = rowptr[n], end = rowptr[n + 1];
    float a0 = 0.f, a1 = 0.f, a2 = 0.f, a3 = 0.f;
    int j = beg;
    for (; j + 16 <= end; j += 16) {
        #pragma unroll
        for (int u = 0; u < 4; ++u) {
            int c = adjc[j + u * 4 + sg];
            ushort4 v = *(const ushort4*)&y2[c * D + fq * 4];
            a0 += bf2f(v.x); a1 += bf2f(v.y); a2 += bf2f(v.z); a3 += bf2f(v.w);
        }
    }
    for (; j + 4 <= end; j += 4) {
        int c = adjc[j + sg];
        ushort4 v = *(const ushort4*)&y2[c * D + fq * 4];
        a0 += bf2f(v.x); a1 += bf2f(v.y); a2 += bf2f(v.z); a3 += bf2f(v.w);
    }
    if (sg < end - j) {
        int c = adjc[j + sg];
        ushort4 v = *(const ushort4*)&y2[c * D + fq * 4];
        a0 += bf2f(v.x); a1 += bf2f(v.y); a2 += bf2f(v.z); a3 += bf2f(v.w);
    }
    a0 += __shfl_xor(a0, 16); a0 += __shfl_xor(a0, 32);
    a1 += __shfl_xor(a1, 16); a1 += __shfl_xor(a1, 32);
    a2 += __shfl_xor(a2, 16); a2 += __shfl_xor(a2, 32);
    a3 += __shfl_xor(a3, 16); a3 += __shfl_xor(a3, 32);
    if (l < 16) {
        ushort4 s = *(const ushort4*)&y2[n * D + l * 4];
        float y0 = bf2f(s.x), y1v = bf2f(s.y), y2v = bf2f(s.z), y3 = bf2f(s.w);
        a0 += y0; a1 += y1v; a2 += y2v; a3 += y3;   // self loop in hop-2 sum
        float di = dis[n], ds = dsi[n];
        float w0 = wsm[0], w1 = wsm[1], w2 = wsm[2];
        float4 xv = *(const float4*)&x[n * D + l * 4];
        float4 o;
        o.x = w0 * xv.x + w1 * (ds * y0) + w2 * (di * a0);
        o.y = w0 * xv.y + w1 * (ds * y1v) + w2 * (di * a1);
        o.z = w0 * xv.z + w1 * (ds * y2v) + w2 * (di * a2);
        o.w = w0 * xv.w + w1 * (ds * y3) + w2 * (di * a3);
        *(float4*)&out[n * D + l * 4] = o;
    }
}

// ---------------- launch ----------------

extern "C" void kernel_launch(void* const* d_in, const int* in_sizes, int n_in,
                              void* d_out, int out_size, void* d_ws, size_t ws_size,
                              hipStream_t stream) {
    const float* x   = (const float*)d_in[0];
    const int*   ei  = (const int*)d_in[1];   // [2, NE]
    const float* hw  = (const float*)d_in[2]; // [3]
    float*       out = (float*)d_out;

    const int* row = ei;       // scatter destination
    const int* col = ei + NE;  // gather source

    char* ws = (char*)d_ws;
    size_t off = 0;
    auto alloc = [&](size_t bytes) { size_t p = off; off += (bytes + 255) & ~(size_t)255; return p; };
    float* wsm    = (float*)(ws + alloc(16));
    int*   bcnt   = (int*)  (ws + alloc((size_t)BKT * 4));
    int*   bcnt2  = (int*)  (ws + alloc((size_t)BKT * 4));
    int*   scanb  = (int*)  (ws + alloc((size_t)(BKT + 1) * 4));
    float* dis    = (float*)(ws + alloc((size_t)NN * 4));
    float* dsi    = (float*)(ws + alloc((size_t)NN * 4));
    u32*   buck   = (u32*)  (ws + alloc((size_t)BKT * CAP * 4));
    u16*   buck2  = (u16*)  (ws + alloc((size_t)BKT * CAP * 2));
    int*   adjc   = (int*)  (ws + alloc((size_t)NE * 4));
    int*   rowptr = (int*)  (ws + alloc((size_t)(NN + 1) * 4));
    u16*   y1     = (u16*)  (ws + alloc((size_t)NN * D * 2));
    u16*   y2     = (u16*)  (ws + alloc((size_t)NN * D * 2));

    hipMemsetAsync(bcnt, 0, (size_t)BKT * 4, stream);
    hipMemsetAsync(bcnt2, 0, (size_t)BKT * 4, stream);

    fused_p1<<<P1_NB, P1_T, 0, stream>>>(row, col, bcnt, bcnt2, buck, buck2);
    deg_count<<<BKT, 1024, 0, stream>>>(bcnt2, buck2, dis, dsi);
    softmax_kernel<<<1, 1, 0, stream>>>(hw, wsm);
    scale_kernel<<<(NN * (D / 4) + 255) / 256, 256, 0, stream>>>((const float4*)x, dis, (ushort4*)y1);
    bscan_kernel<<<1, BKT, 0, stream>>>(bcnt, scanb);
    p2_build<<<BKT, 1024, 0, stream>>>(scanb, buck, adjc, rowptr);

    const int prop_blocks = (NN * 64 + 255) / 256; // 25000
    prop1_kernel<<<prop_blocks, 256, 0, stream>>>(rowptr, adjc, dis, y1, y2);
    prop2_kernel<<<prop_blocks, 256, 0, stream>>>(x, rowptr, adjc, dis, dsi, y2, wsm, out);
}

// Round 11
// 143.385 us; speedup vs baseline: 1.5256x; 1.1506x over previous
//
#include <hip/hip_runtime.h>

#define NN 100000
#define NE 1600000
#define D 64

#define BKT 256                          // buckets (both row- and col-space)
#define BROWS ((NN + BKT - 1) / BKT)     // 391 per bucket (fits 9 bits)
#define CAP 8192                         // slots per bucket (mean 6250, sigma 79)
#define P1_NB 512                        // pass-1 blocks
#define P1_T 1024                        // pass-1 threads per block
#define EPB ((NE + P1_NB - 1) / P1_NB)   // 3125 edges per pass-1 block

typedef unsigned short u16;
typedef unsigned int u32;
typedef __attribute__((ext_vector_type(8))) unsigned short us8;

// ---------------- bf16 helpers (bit-level, RNE) ----------------

__device__ __forceinline__ float bf2f(u16 u) {
    union { u32 i; float f; } x; x.i = ((u32)u) << 16; return x.f;
}
__device__ __forceinline__ u16 f2bf(float f) {
    union { float f; u32 i; } x; x.f = f;
    u32 r = x.i + 0x7FFF + ((x.i >> 16) & 1);   // round-to-nearest-even
    return (u16)(r >> 16);
}

__global__ void softmax_kernel(const float* __restrict__ hw, float* __restrict__ wsm) {
    float m = fmaxf(fmaxf(hw[0], hw[1]), hw[2]);
    float e0 = expf(hw[0] - m), e1 = expf(hw[1] - m), e2 = expf(hw[2] - m);
    float s = e0 + e1 + e2;
    wsm[0] = e0 / s; wsm[1] = e1 / s; wsm[2] = e2 / s;
}

// ---------------- fused pass 1: stage, double-bucket (row & col), scatter ----
__global__ void __launch_bounds__(P1_T) fused_p1(const int* __restrict__ row,
                                                 const int* __restrict__ col,
                                                 int* __restrict__ bcnt,
                                                 int* __restrict__ bcnt2,
                                                 u32* __restrict__ buck,
                                                 u16* __restrict__ buck2) {
    __shared__ int lds_r[EPB];
    __shared__ int lds_c[EPB];
    __shared__ int h[BKT];
    __shared__ int h2[BKT];
    int t = threadIdx.x;
    int beg = blockIdx.x * EPB, end = min(NE, beg + EPB);
    int n = end - beg;
    for (int i = t; i < BKT; i += P1_T) { h[i] = 0; h2[i] = 0; }
    __syncthreads();
    for (int i = t; i < n; i += P1_T) {
        int r = row[beg + i], c = col[beg + i];
        lds_r[i] = r; lds_c[i] = c;
        atomicAdd(&h[r / BROWS], 1);
        atomicAdd(&h2[c / BROWS], 1);
    }
    __syncthreads();
    for (int b = t; b < BKT; b += P1_T) {
        int cl = h[b];
        h[b] = atomicAdd(&bcnt[b], cl);
        int cl2 = h2[b];
        h2[b] = atomicAdd(&bcnt2[b], cl2);
    }
    __syncthreads();
    for (int i = t; i < n; i += P1_T) {
        int r = lds_r[i], c = lds_c[i];
        int b = r / BROWS;
        int pos = atomicAdd(&h[b], 1);
        buck[(size_t)b * CAP + pos] = ((u32)(r - b * BROWS) << 17) | (u32)c;
        int b2 = c / BROWS;
        int pos2 = atomicAdd(&h2[b2], 1);
        buck2[(size_t)b2 * CAP + pos2] = (u16)(c - b2 * BROWS);
    }
}

// Degree count from col-bucketed u16 remainders -> dis = rsqrt(deg+1), dsi = sqrt.
__global__ void __launch_bounds__(1024) deg_count(const int* __restrict__ bcnt2,
                                                  const u16* __restrict__ buck2,
                                                  float* __restrict__ dis,
                                                  float* __restrict__ dsi) {
    __shared__ int ca[BROWS];
    int b = blockIdx.x, t = threadIdx.x;
    int row0 = b * BROWS;
    int nrows = min(BROWS, NN - row0);
    int cntb = bcnt2[b];
    const u16* eb = buck2 + (size_t)b * CAP;
    for (int i = t; i < nrows; i += 1024) ca[i] = 0;
    __syncthreads();
    for (int e = t; e < cntb; e += 1024)
        atomicAdd(&ca[eb[e]], 1);
    __syncthreads();
    if (t < nrows) {
        float dg = (float)(ca[t] + 1);
        dis[row0 + t] = rsqrtf(dg);
        dsi[row0 + t] = sqrtf(dg);
    }
}

// y1 = bf16( dis (x) x )
__global__ void scale_kernel(const float4* __restrict__ x, const float* __restrict__ dis,
                             ushort4* __restrict__ y1) {
    int idx = blockIdx.x * blockDim.x + threadIdx.x;
    if (idx >= NN * (D / 4)) return;
    float s = dis[idx >> 4];
    float4 v = x[idx];
    ushort4 o;
    o.x = f2bf(s * v.x); o.y = f2bf(s * v.y); o.z = f2bf(s * v.z); o.w = f2bf(s * v.w);
    y1[idx] = o;
}

// Exclusive scan of the 256 row-bucket counts.
__global__ void bscan_kernel(const int* __restrict__ bcnt, int* __restrict__ scanb) {
    __shared__ int s[BKT];
    int t = threadIdx.x;
    int v = bcnt[t];
    s[t] = v;
    __syncthreads();
    for (int st = 1; st < BKT; st <<= 1) {
        int u = (t >= st) ? s[t - st] : 0;
        __syncthreads();
        s[t] += u;
        __syncthreads();
    }
    scanb[t] = s[t] - v;
    if (t == BKT - 1) scanb[BKT] = s[t];
}

// Pass 2: one block per bucket — LDS row-count, shfl scan -> rowptr, scatter -> adjc.
__global__ void __launch_bounds__(1024) p2_build(const int* __restrict__ scanb,
                                                 const u32* __restrict__ buck,
                                                 int* __restrict__ adjc,
                                                 int* __restrict__ rowptr) {
    __shared__ int ca[BROWS];
    __shared__ int wsum[16];
    int b = blockIdx.x, t = threadIdx.x;
    int row0 = b * BROWS;
    int nrows = min(BROWS, NN - row0);
    int ebeg = scanb[b];
    int cntb = scanb[b + 1] - ebeg;
    const u32* eb = buck + (size_t)b * CAP;

    for (int i = t; i < nrows; i += 1024) ca[i] = 0;
    __syncthreads();
    for (int e = t; e < cntb; e += 1024)
        atomicAdd(&ca[eb[e] >> 17], 1);
    __syncthreads();
    // shfl-based exclusive scan over nrows (<=1024)
    int v = (t < nrows) ? ca[t] : 0;
    int lane = t & 63, wv = t >> 6;
    int incl = v;
    #pragma unroll
    for (int d = 1; d < 64; d <<= 1) {
        int u = __shfl_up(incl, d);
        if (lane >= d) incl += u;
    }
    if (lane == 63) wsum[wv] = incl;
    __syncthreads();
    if (t < 16) {
        int s = wsum[t];
        #pragma unroll
        for (int d = 1; d < 16; d <<= 1) {
            int u = __shfl_up(s, d, 16);
            if ((t & 15) >= d) s += u;
        }
        wsum[t] = s;
    }
    __syncthreads();
    int excl = ((wv > 0) ? wsum[wv - 1] : 0) + incl - v;
    if (t < nrows) {
        rowptr[row0 + t] = ebeg + excl;
        ca[t] = ebeg + excl;
    }
    if (b == 0 && t == 0) rowptr[NN] = NE;
    __syncthreads();
    for (int e = t; e < cntb; e += 1024) {
        u32 p = eb[e];
        int pos = atomicAdd(&ca[p >> 17], 1);
        adjc[pos] = (int)(p & 0x1FFFFu);
    }
}

// ---------------- propagate kernels (gather, no atomics) ----------------
// TWO nodes per wave: lanes 0-31 -> node 2w, lanes 32-63 -> node 2w+1.
// Per half: sg = (l>>3)&3 edge slot, ho = l&7 feature octet (ushort8, 16B).
// Main loop: 16 edges/half/iter -> 32 cache lines in flight per wave.

__global__ void prop1_kernel(const int* __restrict__ rowptr,
                             const int* __restrict__ adjc,
                             const float* __restrict__ dis,
                             const u16* __restrict__ y1,
                             u16* __restrict__ y2) {
    int tid = blockIdx.x * blockDim.x + threadIdx.x;
    int w = tid >> 6, l = tid & 63;
    int half = l >> 5;
    int n = 2 * w + half;               // grid sized so n < NN always
    int sg = (l >> 3) & 3;
    int ho = l & 7;
    int beg = rowptr[n], end = rowptr[n + 1];
    float a[8] = {0.f, 0.f, 0.f, 0.f, 0.f, 0.f, 0.f, 0.f};
    int j = beg;
    while (true) {                       // 16 edges per half per iter
        bool act = (j + 16 <= end);
        if (!__any(act)) break;
        if (act) {
            int c0 = adjc[j + sg];
            int c1 = adjc[j + 4 + sg];
            int c2 = adjc[j + 8 + sg];
            int c3 = adjc[j + 12 + sg];
            us8 v0 = *(const us8*)&y1[c0 * D + ho * 8];
            us8 v1 = *(const us8*)&y1[c1 * D + ho * 8];
            us8 v2 = *(const us8*)&y1[c2 * D + ho * 8];
            us8 v3 = *(const us8*)&y1[c3 * D + ho * 8];
            #pragma unroll
            for (int k = 0; k < 8; ++k)
                a[k] += (bf2f(v0[k]) + bf2f(v1[k])) + (bf2f(v2[k]) + bf2f(v3[k]));
            j += 16;
        }
    }
    while (true) {                       // 4-edge steps
        bool act = (j + 4 <= end);
        if (!__any(act)) break;
        if (act) {
            int c0 = adjc[j + sg];
            us8 v0 = *(const us8*)&y1[c0 * D + ho * 8];
            #pragma unroll
            for (int k = 0; k < 8; ++k) a[k] += bf2f(v0[k]);
            j += 4;
        }
    }
    if (sg < end - j) {                  // masked tail (<4 edges)
        int c0 = adjc[j + sg];
        us8 v0 = *(const us8*)&y1[c0 * D + ho * 8];
        #pragma unroll
        for (int k = 0; k < 8; ++k) a[k] += bf2f(v0[k]);
    }
    // reduce over sg bits (3,4) within each half
    #pragma unroll
    for (int k = 0; k < 8; ++k) {
        a[k] += __shfl_xor(a[k], 8);
        a[k] += __shfl_xor(a[k], 16);
    }
    if ((l & 31) < 8) {
        us8 s = *(const us8*)&y1[n * D + ho * 8];   // self loop
        float di = dis[n], d2 = di * di;
        us8 o;
        #pragma unroll
        for (int k = 0; k < 8; ++k) o[k] = f2bf(d2 * (a[k] + bf2f(s[k])));
        *(us8*)&y2[n * D + ho * 8] = o;
    }
}

// out = w0*x + w1*(dsi*y2[n]) + w2*di*(y2[n] + sum_c y2[c])
__global__ void prop2_kernel(const float* __restrict__ x,
                             const int* __restrict__ rowptr,
                             const int* __restrict__ adjc,
                             const float* __restrict__ dis,
                             const float* __restrict__ dsi,
                             const u16* __restrict__ y2,
                             const float* __restrict__ wsm,
                             float* __restrict__ out) {
    int tid = blockIdx.x * blockDim.x + threadIdx.x;
    int w = tid >> 6, l = tid & 63;
    int half = l >> 5;
    int n = 2 * w + half;
    int sg = (l >> 3) & 3;
    int ho = l & 7;
    int beg = rowptr[n], end = rowptr[n + 1];
    float a[8] = {0.f, 0.f, 0.f, 0.f, 0.f, 0.f, 0.f, 0.f};
    int j = beg;
    while (true) {
        bool act = (j + 16 <= end);
        if (!__any(act)) break;
        if (act) {
            int c0 = adjc[j + sg];
            int c1 = adjc[j + 4 + sg];
            int c2 = adjc[j + 8 + sg];
            int c3 = adjc[j + 12 + sg];
            us8 v0 = *(const us8*)&y2[c0 * D + ho * 8];
            us8 v1 = *(const us8*)&y2[c1 * D + ho * 8];
            us8 v2 = *(const us8*)&y2[c2 * D + ho * 8];
            us8 v3 = *(const us8*)&y2[c3 * D + ho * 8];
            #pragma unroll
            for (int k = 0; k < 8; ++k)
                a[k] += (bf2f(v0[k]) + bf2f(v1[k])) + (bf2f(v2[k]) + bf2f(v3[k]));
            j += 16;
        }
    }
    while (true) {
        bool act = (j + 4 <= end);
        if (!__any(act)) break;
        if (act) {
            int c0 = adjc[j + sg];
            us8 v0 = *(const us8*)&y2[c0 * D + ho * 8];
            #pragma unroll
            for (int k = 0; k < 8; ++k) a[k] += bf2f(v0[k]);
            j += 4;
        }
    }
    if (sg < end - j) {
        int c0 = adjc[j + sg];
        us8 v0 = *(const us8*)&y2[c0 * D + ho * 8];
        #pragma unroll
        for (int k = 0; k < 8; ++k) a[k] += bf2f(v0[k]);
    }
    #pragma unroll
    for (int k = 0; k < 8; ++k) {
        a[k] += __shfl_xor(a[k], 8);
        a[k] += __shfl_xor(a[k], 16);
    }
    if ((l & 31) < 8) {
        us8 s = *(const us8*)&y2[n * D + ho * 8];
        float yk[8];
        #pragma unroll
        for (int k = 0; k < 8; ++k) { yk[k] = bf2f(s[k]); a[k] += yk[k]; }
        float di = dis[n], ds = dsi[n];
        float w0 = wsm[0], w1 = wsm[1], w2 = wsm[2];
        float4 xv0 = *(const float4*)&x[n * D + ho * 8];
        float4 xv1 = *(const float4*)&x[n * D + ho * 8 + 4];
        float4 o0, o1;
        o0.x = w0 * xv0.x + w1 * (ds * yk[0]) + w2 * (di * a[0]);
        o0.y = w0 * xv0.y + w1 * (ds * yk[1]) + w2 * (di * a[1]);
        o0.z = w0 * xv0.z + w1 * (ds * yk[2]) + w2 * (di * a[2]);
        o0.w = w0 * xv0.w + w1 * (ds * yk[3]) + w2 * (di * a[3]);
        o1.x = w0 * xv1.x + w1 * (ds * yk[4]) + w2 * (di * a[4]);
        o1.y = w0 * xv1.y + w1 * (ds * yk[5]) + w2 * (di * a[5]);
        o1.z = w0 * xv1.z + w1 * (ds * yk[6]) + w2 * (di * a[6]);
        o1.w = w0 * xv1.w + w1 * (ds * yk[7]) + w2 * (di * a[7]);
        *(float4*)&out[n * D + ho * 8] = o0;
        *(float4*)&out[n * D + ho * 8 + 4] = o1;
    }
}

// ---------------- launch ----------------

extern "C" void kernel_launch(void* const* d_in, const int* in_sizes, int n_in,
                              void* d_out, int out_size, void* d_ws, size_t ws_size,
                              hipStream_t stream) {
    const float* x   = (const float*)d_in[0];
    const int*   ei  = (const int*)d_in[1];   // [2, NE]
    const float* hw  = (const float*)d_in[2]; // [3]
    float*       out = (float*)d_out;

    const int* row = ei;       // scatter destination
    const int* col = ei + NE;  // gather source

    char* ws = (char*)d_ws;
    size_t off = 0;
    auto alloc = [&](size_t bytes) { size_t p = off; off += (bytes + 255) & ~(size_t)255; return p; };
    float* wsm    = (float*)(ws + alloc(16));
    int*   bcnt   = (int*)  (ws + alloc((size_t)BKT * 4));
    int*   bcnt2  = (int*)  (ws + alloc((size_t)BKT * 4));
    int*   scanb  = (int*)  (ws + alloc((size_t)(BKT + 1) * 4));
    float* dis    = (float*)(ws + alloc((size_t)NN * 4));
    float* dsi    = (float*)(ws + alloc((size_t)NN * 4));
    u32*   buck   = (u32*)  (ws + alloc((size_t)BKT * CAP * 4));
    u16*   buck2  = (u16*)  (ws + alloc((size_t)BKT * CAP * 2));
    int*   adjc   = (int*)  (ws + alloc((size_t)NE * 4));
    int*   rowptr = (int*)  (ws + alloc((size_t)(NN + 1) * 4));
    u16*   y1     = (u16*)  (ws + alloc((size_t)NN * D * 2));
    u16*   y2     = (u16*)  (ws + alloc((size_t)NN * D * 2));

    hipMemsetAsync(bcnt, 0, (size_t)BKT * 4, stream);
    hipMemsetAsync(bcnt2, 0, (size_t)BKT * 4, stream);

    fused_p1<<<P1_NB, P1_T, 0, stream>>>(row, col, bcnt, bcnt2, buck, buck2);
    deg_count<<<BKT, 1024, 0, stream>>>(bcnt2, buck2, dis, dsi);
    softmax_kernel<<<1, 1, 0, stream>>>(hw, wsm);
    scale_kernel<<<(NN * (D / 4) + 255) / 256, 256, 0, stream>>>((const float4*)x, dis, (ushort4*)y1);
    bscan_kernel<<<1, BKT, 0, stream>>>(bcnt, scanb);
    p2_build<<<BKT, 1024, 0, stream>>>(scanb, buck, adjc, rowptr);

    // 2 nodes per wave: NN/2 waves = 50000; 4 waves per 256-thread block.
    const int prop_blocks = (NN / 2 + 3) / 4; // 12500
    prop1_kernel<<<prop_blocks, 256, 0, stream>>>(rowptr, adjc, dis, y1, y2);
    prop2_kernel<<<prop_blocks, 256, 0, stream>>>(x, rowptr, adjc, dis, dsi, y2, wsm, out);
}

// Round 12
// 126.698 us; speedup vs baseline: 1.7265x; 1.1317x over previous
//
#include <hip/hip_runtime.h>

#define NN 100000
#define NE 1600000
#define D 64

#define BKT 256                          // buckets (both row- and col-space)
#define BROWS ((NN + BKT - 1) / BKT)     // 391 per bucket (fits 9 bits)
#define CAP 8192                         // buck slots per bucket (mean 6250, sigma 79)
#define PADCAP 8192                      // adjc slots per bucket (padded rows, max ~7900)
#define P1_NB 512                        // pass-1 blocks
#define P1_T 1024                        // pass-1 threads per block
#define EPB ((NE + P1_NB - 1) / P1_NB)   // 3125 edges per pass-1 block

typedef unsigned short u16;
typedef unsigned int u32;
typedef unsigned char u8;
typedef __attribute__((ext_vector_type(8))) unsigned short us8;

// ---------------- bf16 helpers (bit-level, RNE) ----------------

__device__ __forceinline__ float bf2f(u16 u) {
    union { u32 i; float f; } x; x.i = ((u32)u) << 16; return x.f;
}
__device__ __forceinline__ u16 f2bf(float f) {
    union { float f; u32 i; } x; x.f = f;
    u32 r = x.i + 0x7FFF + ((x.i >> 16) & 1);   // round-to-nearest-even
    return (u16)(r >> 16);
}

__global__ void softmax_kernel(const float* __restrict__ hw, float* __restrict__ wsm) {
    float m = fmaxf(fmaxf(hw[0], hw[1]), hw[2]);
    float e0 = expf(hw[0] - m), e1 = expf(hw[1] - m), e2 = expf(hw[2] - m);
    float s = e0 + e1 + e2;
    wsm[0] = e0 / s; wsm[1] = e1 / s; wsm[2] = e2 / s;
}

// ---------------- fused pass 1: stage, double-bucket, LDS-sort, coalesced write ---
__global__ void __launch_bounds__(P1_T) fused_p1(const int* __restrict__ row,
                                                 const int* __restrict__ col,
                                                 int* __restrict__ bcnt,
                                                 int* __restrict__ bcnt2,
                                                 u32* __restrict__ buck,
                                                 u16* __restrict__ buck2) {
    __shared__ int lds_r[EPB];
    __shared__ int lds_c[EPB];
    __shared__ u32 st1[EPB];
    __shared__ u16 st2[EPB];
    __shared__ u8  sb1[EPB];
    __shared__ u8  sb2[EPB];
    __shared__ int h[BKT], h2[BKT];        // counts -> inclusive scan -> cursors
    __shared__ int hoff[BKT], hoff2[BKT];  // local exclusive offsets
    __shared__ int resv[BKT], resv2[BKT];  // global base reservations
    int t = threadIdx.x;
    int beg = blockIdx.x * EPB, end = min(NE, beg + EPB);
    int n = end - beg;
    for (int i = t; i < BKT; i += P1_T) { h[i] = 0; h2[i] = 0; }
    __syncthreads();
    // stage + both bucket histograms
    for (int i = t; i < n; i += P1_T) {
        int r = row[beg + i], c = col[beg + i];
        lds_r[i] = r; lds_c[i] = c;
        atomicAdd(&h[r / BROWS], 1);
        atomicAdd(&h2[c / BROWS], 1);
    }
    __syncthreads();
    // dual in-place Hillis-Steele inclusive scan (threads 0-255: h, 256-511: h2)
    int id = t & 255;
    int side = t >> 8;
    int* arr = (side == 0) ? h : h2;
    int myc = (side < 2) ? arr[id] : 0;
    for (int st = 1; st < BKT; st <<= 1) {
        int u = 0;
        if (side < 2 && id >= st) u = arr[id - st];
        __syncthreads();
        if (side < 2) arr[id] += u;
        __syncthreads();
    }
    if (side == 0) {
        hoff[id] = h[id] - myc;
        resv[id] = atomicAdd(&bcnt[id], myc);
    } else if (side == 1) {
        hoff2[id] = h2[id] - myc;
        resv2[id] = atomicAdd(&bcnt2[id], myc);
    }
    __syncthreads();
    // reset cursors to local exclusive offsets
    if (t < BKT) h[t] = hoff[t];
    else if (t < 2 * BKT) h2[t - BKT] = hoff2[t - BKT];
    __syncthreads();
    // scatter into LDS staged arrays (bucket-sorted)
    for (int i = t; i < n; i += P1_T) {
        int r = lds_r[i], c = lds_c[i];
        int b1 = r / BROWS;
        int pos = atomicAdd(&h[b1], 1);
        st1[pos] = ((u32)(r - b1 * BROWS) << 17) | (u32)c;
        sb1[pos] = (u8)b1;
        int b2 = c / BROWS;
        int pos2 = atomicAdd(&h2[b2], 1);
        st2[pos2] = (u16)(c - b2 * BROWS);
        sb2[pos2] = (u8)b2;
    }
    __syncthreads();
    // coalesced write-out (consecutive i -> consecutive dest within bucket runs)
    for (int i = t; i < n; i += P1_T) {
        int b1 = sb1[i];
        buck[(size_t)b1 * CAP + resv[b1] + (i - hoff[b1])] = st1[i];
        int b2 = sb2[i];
        buck2[(size_t)b2 * CAP + resv2[b2] + (i - hoff2[b2])] = st2[i];
    }
}

// Degree count from col-bucketed u16 remainders -> dis = rsqrt(deg+1), dsi = sqrt.
__global__ void __launch_bounds__(1024) deg_count(const int* __restrict__ bcnt2,
                                                  const u16* __restrict__ buck2,
                                                  float* __restrict__ dis,
                                                  float* __restrict__ dsi) {
    __shared__ int ca[BROWS];
    int b = blockIdx.x, t = threadIdx.x;
    int row0 = b * BROWS;
    int nrows = min(BROWS, NN - row0);
    int cntb = bcnt2[b];
    const u16* eb = buck2 + (size_t)b * CAP;
    for (int i = t; i < nrows; i += 1024) ca[i] = 0;
    __syncthreads();
    for (int e = t; e < cntb; e += 1024)
        atomicAdd(&ca[eb[e]], 1);
    __syncthreads();
    if (t < nrows) {
        float dg = (float)(ca[t] + 1);
        dis[row0 + t] = rsqrtf(dg);
        dsi[row0 + t] = sqrtf(dg);
    }
}

// y1 = bf16( dis (x) x ); also zeroes the sentinel row NN in y1 AND y2.
__global__ void scale_kernel(const float4* __restrict__ x, const float* __restrict__ dis,
                             ushort4* __restrict__ y1, ushort4* __restrict__ y2) {
    int idx = blockIdx.x * blockDim.x + threadIdx.x;
    if (idx >= (NN + 1) * (D / 4)) return;
    if (idx >= NN * (D / 4)) {          // sentinel row
        ushort4 z = {0, 0, 0, 0};
        y1[idx] = z; y2[idx] = z;
        return;
    }
    float s = dis[idx >> 4];
    float4 v = x[idx];
    ushort4 o;
    o.x = f2bf(s * v.x); o.y = f2bf(s * v.y); o.z = f2bf(s * v.z); o.w = f2bf(s * v.w);
    y1[idx] = o;
}

// Pass 2: one block per bucket — row-count, padded shfl scan -> rowbe(int2),
// sentinel-pad, scatter -> adjc at fixed bucket base b*PADCAP.
__global__ void __launch_bounds__(1024) p2_build(const int* __restrict__ bcnt,
                                                 const u32* __restrict__ buck,
                                                 int* __restrict__ adjc,
                                                 int2* __restrict__ rowbe) {
    __shared__ int ca[BROWS];
    __shared__ int wsum[16];
    int b = blockIdx.x, t = threadIdx.x;
    int row0 = b * BROWS;
    int nrows = min(BROWS, NN - row0);
    int cntb = bcnt[b];
    const u32* eb = buck + (size_t)b * CAP;

    for (int i = t; i < nrows; i += 1024) ca[i] = 0;
    __syncthreads();
    for (int e = t; e < cntb; e += 1024)
        atomicAdd(&ca[eb[e] >> 17], 1);
    __syncthreads();
    int v = (t < nrows) ? ca[t] : 0;
    int vp = (v + 3) & ~3;               // pad row length to multiple of 4
    int lane = t & 63, wv = t >> 6;
    int incl = vp;
    #pragma unroll
    for (int d = 1; d < 64; d <<= 1) {
        int u = __shfl_up(incl, d);
        if (lane >= d) incl += u;
    }
    if (lane == 63) wsum[wv] = incl;
    __syncthreads();
    if (t < 16) {
        int s = wsum[t];
        #pragma unroll
        for (int d = 1; d < 16; d <<= 1) {
            int u = __shfl_up(s, d, 16);
            if (t >= d) s += u;
        }
        wsum[t] = s;
    }
    __syncthreads();
    int excl = ((wv > 0) ? wsum[wv - 1] : 0) + incl - vp;
    if (t < nrows) {
        int base = b * PADCAP + excl;
        rowbe[row0 + t] = make_int2(base, base + vp);
        for (int p = base + v; p < base + vp; ++p) adjc[p] = NN;  // sentinel pads
        ca[t] = base;                    // cursor = global position
    }
    __syncthreads();
    for (int e = t; e < cntb; e += 1024) {
        u32 p = eb[e];
        int pos = atomicAdd(&ca[p >> 17], 1);
        adjc[pos] = (int)(p & 0x1FFFFu);
    }
}

// ---------------- propagate kernels (gather, no atomics) ----------------
// TWO nodes per wave (lanes 0-31 / 32-63). Per half: sg=(l>>3)&3, ho=l&7.
// Rows padded to multiple of 4 -> lane loads int4 of adjc (4 edges, 16B aligned).
// Main loop: 32 edges/half/iter, 8 independent 16B gathers per lane in flight.

__global__ void prop1_kernel(const int2* __restrict__ rowbe,
                             const int* __restrict__ adjc,
                             const float* __restrict__ dis,
                             const u16* __restrict__ y1,
                             u16* __restrict__ y2) {
    int tid = blockIdx.x * blockDim.x + threadIdx.x;
    int w = tid >> 6, l = tid & 63;
    int half = l >> 5;
    int n = 2 * w + half;
    int sg = (l >> 3) & 3;
    int ho = l & 7;
    int2 be = rowbe[n];
    int j = be.x, end = be.y;
    float a[8] = {0.f, 0.f, 0.f, 0.f, 0.f, 0.f, 0.f, 0.f};
    while (j + 32 <= end) {
        int4 c0 = *(const int4*)&adjc[j + sg * 4];
        int4 c1 = *(const int4*)&adjc[j + 16 + sg * 4];
        us8 v0 = *(const us8*)&y1[c0.x * D + ho * 8];
        us8 v1 = *(const us8*)&y1[c0.y * D + ho * 8];
        us8 v2 = *(const us8*)&y1[c0.z * D + ho * 8];
        us8 v3 = *(const us8*)&y1[c0.w * D + ho * 8];
        us8 v4 = *(const us8*)&y1[c1.x * D + ho * 8];
        us8 v5 = *(const us8*)&y1[c1.y * D + ho * 8];
        us8 v6 = *(const us8*)&y1[c1.z * D + ho * 8];
        us8 v7 = *(const us8*)&y1[c1.w * D + ho * 8];
        #pragma unroll
        for (int k = 0; k < 8; ++k)
            a[k] += ((bf2f(v0[k]) + bf2f(v1[k])) + (bf2f(v2[k]) + bf2f(v3[k])))
                  + ((bf2f(v4[k]) + bf2f(v5[k])) + (bf2f(v6[k]) + bf2f(v7[k])));
        j += 32;
    }
    if (j + 16 <= end) {
        int4 c0 = *(const int4*)&adjc[j + sg * 4];
        us8 v0 = *(const us8*)&y1[c0.x * D + ho * 8];
        us8 v1 = *(const us8*)&y1[c0.y * D + ho * 8];
        us8 v2 = *(const us8*)&y1[c0.z * D + ho * 8];
        us8 v3 = *(const us8*)&y1[c0.w * D + ho * 8];
        #pragma unroll
        for (int k = 0; k < 8; ++k)
            a[k] += (bf2f(v0[k]) + bf2f(v1[k])) + (bf2f(v2[k]) + bf2f(v3[k]));
        j += 16;
    }
    while (j + 4 <= end) {
        int c = adjc[j + sg];
        us8 v0 = *(const us8*)&y1[c * D + ho * 8];
        #pragma unroll
        for (int k = 0; k < 8; ++k) a[k] += bf2f(v0[k]);
        j += 4;
    }
    #pragma unroll
    for (int k = 0; k < 8; ++k) {
        a[k] += __shfl_xor(a[k], 8);
        a[k] += __shfl_xor(a[k], 16);
    }
    if ((l & 31) < 8) {
        us8 s = *(const us8*)&y1[n * D + ho * 8];   // self loop
        float di = dis[n], d2 = di * di;
        us8 o;
        #pragma unroll
        for (int k = 0; k < 8; ++k) o[k] = f2bf(d2 * (a[k] + bf2f(s[k])));
        *(us8*)&y2[n * D + ho * 8] = o;
    }
}

// out = w0*x + w1*(dsi*y2[n]) + w2*di*(y2[n] + sum_c y2[c])
__global__ void prop2_kernel(const float* __restrict__ x,
                             const int2* __restrict__ rowbe,
                             const int* __restrict__ adjc,
                             const float* __restrict__ dis,
                             const float* __restrict__ dsi,
                             const u16* __restrict__ y2,
                             const float* __restrict__ wsm,
                             float* __restrict__ out) {
    int tid = blockIdx.x * blockDim.x + threadIdx.x;
    int w = tid >> 6, l = tid & 63;
    int half = l >> 5;
    int n = 2 * w + half;
    int sg = (l >> 3) & 3;
    int ho = l & 7;
    int2 be = rowbe[n];
    int j = be.x, end = be.y;
    float a[8] = {0.f, 0.f, 0.f, 0.f, 0.f, 0.f, 0.f, 0.f};
    while (j + 32 <= end) {
        int4 c0 = *(const int4*)&adjc[j + sg * 4];
        int4 c1 = *(const int4*)&adjc[j + 16 + sg * 4];
        us8 v0 = *(const us8*)&y2[c0.x * D + ho * 8];
        us8 v1 = *(const us8*)&y2[c0.y * D + ho * 8];
        us8 v2 = *(const us8*)&y2[c0.z * D + ho * 8];
        us8 v3 = *(const us8*)&y2[c0.w * D + ho * 8];
        us8 v4 = *(const us8*)&y2[c1.x * D + ho * 8];
        us8 v5 = *(const us8*)&y2[c1.y * D + ho * 8];
        us8 v6 = *(const us8*)&y2[c1.z * D + ho * 8];
        us8 v7 = *(const us8*)&y2[c1.w * D + ho * 8];
        #pragma unroll
        for (int k = 0; k < 8; ++k)
            a[k] += ((bf2f(v0[k]) + bf2f(v1[k])) + (bf2f(v2[k]) + bf2f(v3[k])))
                  + ((bf2f(v4[k]) + bf2f(v5[k])) + (bf2f(v6[k]) + bf2f(v7[k])));
        j += 32;
    }
    if (j + 16 <= end) {
        int4 c0 = *(const int4*)&adjc[j + sg * 4];
        us8 v0 = *(const us8*)&y2[c0.x * D + ho * 8];
        us8 v1 = *(const us8*)&y2[c0.y * D + ho * 8];
        us8 v2 = *(const us8*)&y2[c0.z * D + ho * 8];
        us8 v3 = *(const us8*)&y2[c0.w * D + ho * 8];
        #pragma unroll
        for (int k = 0; k < 8; ++k)
            a[k] += (bf2f(v0[k]) + bf2f(v1[k])) + (bf2f(v2[k]) + bf2f(v3[k]));
        j += 16;
    }
    while (j + 4 <= end) {
        int c = adjc[j + sg];
        us8 v0 = *(const us8*)&y2[c * D + ho * 8];
        #pragma unroll
        for (int k = 0; k < 8; ++k) a[k] += bf2f(v0[k]);
        j += 4;
    }
    #pragma unroll
    for (int k = 0; k < 8; ++k) {
        a[k] += __shfl_xor(a[k], 8);
        a[k] += __shfl_xor(a[k], 16);
    }
    if ((l & 31) < 8) {
        us8 s = *(const us8*)&y2[n * D + ho * 8];
        float yk[8];
        #pragma unroll
        for (int k = 0; k < 8; ++k) { yk[k] = bf2f(s[k]); a[k] += yk[k]; }
        float di = dis[n], ds = dsi[n];
        float w0 = wsm[0], w1 = wsm[1], w2 = wsm[2];
        float4 xv0 = *(const float4*)&x[n * D + ho * 8];
        float4 xv1 = *(const float4*)&x[n * D + ho * 8 + 4];
        float4 o0, o1;
        o0.x = w0 * xv0.x + w1 * (ds * yk[0]) + w2 * (di * a[0]);
        o0.y = w0 * xv0.y + w1 * (ds * yk[1]) + w2 * (di * a[1]);
        o0.z = w0 * xv0.z + w1 * (ds * yk[2]) + w2 * (di * a[2]);
        o0.w = w0 * xv0.w + w1 * (ds * yk[3]) + w2 * (di * a[3]);
        o1.x = w0 * xv1.x + w1 * (ds * yk[4]) + w2 * (di * a[4]);
        o1.y = w0 * xv1.y + w1 * (ds * yk[5]) + w2 * (di * a[5]);
        o1.z = w0 * xv1.z + w1 * (ds * yk[6]) + w2 * (di * a[6]);
        o1.w = w0 * xv1.w + w1 * (ds * yk[7]) + w2 * (di * a[7]);
        *(float4*)&out[n * D + ho * 8] = o0;
        *(float4*)&out[n * D + ho * 8 + 4] = o1;
    }
}

// ---------------- launch ----------------

extern "C" void kernel_launch(void* const* d_in, const int* in_sizes, int n_in,
                              void* d_out, int out_size, void* d_ws, size_t ws_size,
                              hipStream_t stream) {
    const float* x   = (const float*)d_in[0];
    const int*   ei  = (const int*)d_in[1];   // [2, NE]
    const float* hw  = (const float*)d_in[2]; // [3]
    float*       out = (float*)d_out;

    const int* row = ei;       // scatter destination
    const int* col = ei + NE;  // gather source

    char* ws = (char*)d_ws;
    size_t off = 0;
    auto alloc = [&](size_t bytes) { size_t p = off; off += (bytes + 255) & ~(size_t)255; return p; };
    float* wsm    = (float*)(ws + alloc(16));
    int*   bcnt   = (int*)  (ws + alloc((size_t)BKT * 4));
    int*   bcnt2  = (int*)  (ws + alloc((size_t)BKT * 4));
    float* dis    = (float*)(ws + alloc((size_t)NN * 4));
    float* dsi    = (float*)(ws + alloc((size_t)NN * 4));
    u32*   buck   = (u32*)  (ws + alloc((size_t)BKT * CAP * 4));
    u16*   buck2  = (u16*)  (ws + alloc((size_t)BKT * CAP * 2));
    int*   adjc   = (int*)  (ws + alloc((size_t)BKT * PADCAP * 4));
    int2*  rowbe  = (int2*) (ws + alloc((size_t)NN * 8));
    u16*   y1     = (u16*)  (ws + alloc((size_t)(NN + 1) * D * 2));
    u16*   y2     = (u16*)  (ws + alloc((size_t)(NN + 1) * D * 2));

    hipMemsetAsync(bcnt, 0, (size_t)BKT * 4, stream);
    hipMemsetAsync(bcnt2, 0, (size_t)BKT * 4, stream);

    fused_p1<<<P1_NB, P1_T, 0, stream>>>(row, col, bcnt, bcnt2, buck, buck2);
    deg_count<<<BKT, 1024, 0, stream>>>(bcnt2, buck2, dis, dsi);
    softmax_kernel<<<1, 1, 0, stream>>>(hw, wsm);
    scale_kernel<<<((NN + 1) * (D / 4) + 255) / 256, 256, 0, stream>>>(
        (const float4*)x, dis, (ushort4*)y1, (ushort4*)y2);
    p2_build<<<BKT, 1024, 0, stream>>>(bcnt, buck, adjc, rowbe);

    // 2 nodes per wave: NN/2 waves; 4 waves per 256-thread block.
    const int prop_blocks = (NN / 2 + 3) / 4; // 12500
    prop1_kernel<<<prop_blocks, 256, 0, stream>>>(rowbe, adjc, dis, y1, y2);
    prop2_kernel<<<prop_blocks, 256, 0, stream>>>(x, rowbe, adjc, dis, dsi, y2, wsm, out);
}

// Round 13
// 117.011 us; speedup vs baseline: 1.8695x; 1.0828x over previous
//
#include <hip/hip_runtime.h>

#define NN 100000
#define NE 1600000
#define D 64

#define BKT 256                          // buckets (both row- and col-space)
#define BROWS ((NN + BKT - 1) / BKT)     // 391 per bucket (fits 9 bits)
#define CAP 8192                         // buck slots per bucket (mean 6250, sigma 79)
#define PADCAP 12288                     // adjc slots per bucket (rows padded to x16, mean ~8950)
#define P1_NB 512                        // pass-1 blocks
#define P1_T 1024                        // pass-1 threads per block
#define EPB ((NE + P1_NB - 1) / P1_NB)   // 3125 edges per pass-1 block

typedef unsigned short u16;
typedef unsigned int u32;
typedef unsigned char u8;
typedef __attribute__((ext_vector_type(8))) unsigned short us8;

// ---------------- bf16 helpers (bit-level, RNE) ----------------

__device__ __forceinline__ float bf2f(u16 u) {
    union { u32 i; float f; } x; x.i = ((u32)u) << 16; return x.f;
}
__device__ __forceinline__ u16 f2bf(float f) {
    union { float f; u32 i; } x; x.f = f;
    u32 r = x.i + 0x7FFF + ((x.i >> 16) & 1);   // round-to-nearest-even
    return (u16)(r >> 16);
}

// Setup: zero bucket counters + softmax of the 3 hop weights (replaces 2 memsets + softmax).
__global__ void setup_kernel(const float* __restrict__ hw, float* __restrict__ wsm,
                             int* __restrict__ bcnt, int* __restrict__ bcnt2) {
    int t = threadIdx.x;
    if (t < BKT) bcnt[t] = 0;
    else if (t < 2 * BKT) bcnt2[t - BKT] = 0;
    else if (t == 2 * BKT) {
        float m = fmaxf(fmaxf(hw[0], hw[1]), hw[2]);
        float e0 = expf(hw[0] - m), e1 = expf(hw[1] - m), e2 = expf(hw[2] - m);
        float s = e0 + e1 + e2;
        wsm[0] = e0 / s; wsm[1] = e1 / s; wsm[2] = e2 / s;
    }
}

// ---------------- fused pass 1: stage, double-bucket, LDS-sort, coalesced write ---
__global__ void __launch_bounds__(P1_T) fused_p1(const int* __restrict__ row,
                                                 const int* __restrict__ col,
                                                 int* __restrict__ bcnt,
                                                 int* __restrict__ bcnt2,
                                                 u32* __restrict__ buck,
                                                 u16* __restrict__ buck2) {
    __shared__ int lds_r[EPB];
    __shared__ int lds_c[EPB];
    __shared__ u32 st1[EPB];
    __shared__ u16 st2[EPB];
    __shared__ u8  sb1[EPB];
    __shared__ u8  sb2[EPB];
    __shared__ int h[BKT], h2[BKT];        // counts -> inclusive scan -> cursors
    __shared__ int hoff[BKT], hoff2[BKT];  // local exclusive offsets
    __shared__ int resv[BKT], resv2[BKT];  // global base reservations
    int t = threadIdx.x;
    int beg = blockIdx.x * EPB, end = min(NE, beg + EPB);
    int n = end - beg;
    for (int i = t; i < BKT; i += P1_T) { h[i] = 0; h2[i] = 0; }
    __syncthreads();
    for (int i = t; i < n; i += P1_T) {
        int r = row[beg + i], c = col[beg + i];
        lds_r[i] = r; lds_c[i] = c;
        atomicAdd(&h[r / BROWS], 1);
        atomicAdd(&h2[c / BROWS], 1);
    }
    __syncthreads();
    // dual in-place Hillis-Steele inclusive scan (threads 0-255: h, 256-511: h2)
    int id = t & 255;
    int side = t >> 8;
    int* arr = (side == 0) ? h : h2;
    int myc = (side < 2) ? arr[id] : 0;
    for (int st = 1; st < BKT; st <<= 1) {
        int u = 0;
        if (side < 2 && id >= st) u = arr[id - st];
        __syncthreads();
        if (side < 2) arr[id] += u;
        __syncthreads();
    }
    if (side == 0) {
        hoff[id] = h[id] - myc;
        resv[id] = atomicAdd(&bcnt[id], myc);
    } else if (side == 1) {
        hoff2[id] = h2[id] - myc;
        resv2[id] = atomicAdd(&bcnt2[id], myc);
    }
    __syncthreads();
    if (t < BKT) h[t] = hoff[t];
    else if (t < 2 * BKT) h2[t - BKT] = hoff2[t - BKT];
    __syncthreads();
    for (int i = t; i < n; i += P1_T) {
        int r = lds_r[i], c = lds_c[i];
        int b1 = r / BROWS;
        int pos = atomicAdd(&h[b1], 1);
        st1[pos] = ((u32)(r - b1 * BROWS) << 17) | (u32)c;
        sb1[pos] = (u8)b1;
        int b2 = c / BROWS;
        int pos2 = atomicAdd(&h2[b2], 1);
        st2[pos2] = (u16)(c - b2 * BROWS);
        sb2[pos2] = (u8)b2;
    }
    __syncthreads();
    for (int i = t; i < n; i += P1_T) {
        int b1 = sb1[i];
        buck[(size_t)b1 * CAP + resv[b1] + (i - hoff[b1])] = st1[i];
        int b2 = sb2[i];
        buck2[(size_t)b2 * CAP + resv2[b2] + (i - hoff2[b2])] = st2[i];
    }
}

// Fused degree + scale: per col-bucket, LDS count -> dis/dsi, then y1 = bf16(dis*x)
// for the same row range. Last block also zeroes the sentinel row NN in y1/y2.
__global__ void __launch_bounds__(1024) deg_scale(const int* __restrict__ bcnt2,
                                                  const u16* __restrict__ buck2,
                                                  float* __restrict__ dis,
                                                  float* __restrict__ dsi,
                                                  const float4* __restrict__ x,
                                                  ushort4* __restrict__ y1,
                                                  ushort4* __restrict__ y2) {
    __shared__ int ca[BROWS];
    int b = blockIdx.x, t = threadIdx.x;
    int row0 = b * BROWS;
    int nrows = min(BROWS, NN - row0);
    int cntb = bcnt2[b];
    const u16* eb = buck2 + (size_t)b * CAP;
    for (int i = t; i < nrows; i += 1024) ca[i] = 0;
    __syncthreads();
    for (int e = t; e < cntb; e += 1024)
        atomicAdd(&ca[eb[e]], 1);
    __syncthreads();
    if (t < nrows) {
        float dg = (float)(ca[t] + 1);     // +1 self loop, always > 0
        dis[row0 + t] = rsqrtf(dg);
        dsi[row0 + t] = sqrtf(dg);
    }
    int items = nrows * 16;                 // float4 quads in this row range
    for (int i = t; i < items; i += 1024) {
        int r = i >> 4;
        float s = rsqrtf((float)(ca[r] + 1));
        int gidx = (row0 + r) * 16 + (i & 15);
        float4 v = x[gidx];
        ushort4 o;
        o.x = f2bf(s * v.x); o.y = f2bf(s * v.y); o.z = f2bf(s * v.z); o.w = f2bf(s * v.w);
        y1[gidx] = o;
    }
    if (b == BKT - 1 && t < 16) {           // sentinel row NN
        ushort4 z = {0, 0, 0, 0};
        y1[NN * 16 + t] = z;
        y2[NN * 16 + t] = z;
    }
}

// Pass 2: one block per bucket — row-count, padded (x16) shfl scan -> rowbe(int2),
// sentinel-pad, scatter -> adjc at fixed bucket base b*PADCAP.
__global__ void __launch_bounds__(1024) p2_build(const int* __restrict__ bcnt,
                                                 const u32* __restrict__ buck,
                                                 int* __restrict__ adjc,
                                                 int2* __restrict__ rowbe) {
    __shared__ int ca[BROWS];
    __shared__ int wsum[16];
    int b = blockIdx.x, t = threadIdx.x;
    int row0 = b * BROWS;
    int nrows = min(BROWS, NN - row0);
    int cntb = bcnt[b];
    const u32* eb = buck + (size_t)b * CAP;

    for (int i = t; i < nrows; i += 1024) ca[i] = 0;
    __syncthreads();
    for (int e = t; e < cntb; e += 1024)
        atomicAdd(&ca[eb[e] >> 17], 1);
    __syncthreads();
    int v = (t < nrows) ? ca[t] : 0;
    int vp = (v + 15) & ~15;             // pad row length to multiple of 16
    int lane = t & 63, wv = t >> 6;
    int incl = vp;
    #pragma unroll
    for (int d = 1; d < 64; d <<= 1) {
        int u = __shfl_up(incl, d);
        if (lane >= d) incl += u;
    }
    if (lane == 63) wsum[wv] = incl;
    __syncthreads();
    if (t < 16) {
        int s = wsum[t];
        #pragma unroll
        for (int d = 1; d < 16; d <<= 1) {
            int u = __shfl_up(s, d, 16);
            if (t >= d) s += u;
        }
        wsum[t] = s;
    }
    __syncthreads();
    int excl = ((wv > 0) ? wsum[wv - 1] : 0) + incl - vp;
    if (t < nrows) {
        int base = b * PADCAP + excl;
        rowbe[row0 + t] = make_int2(base, base + vp);
        for (int p = base + v; p < base + vp; ++p) adjc[p] = NN;  // sentinel pads
        ca[t] = base;                    // cursor = global position
    }
    __syncthreads();
    for (int e = t; e < cntb; e += 1024) {
        u32 p = eb[e];
        int pos = atomicAdd(&ca[p >> 17], 1);
        adjc[pos] = (int)(p & 0x1FFFFu);
    }
}

// ---------------- propagate kernels (gather, no atomics) ----------------
// TWO nodes per wave (lanes 0-31 / 32-63). Per half: sg=(l>>3)&3, ho=l&7.
// Rows padded to x16 -> uniform loop of {int4 adjc + 4 us8 gathers}, no tails.
// Sentinel edges hit the zeroed row NN (one hot line, L1-resident).

__global__ void prop1_kernel(const int2* __restrict__ rowbe,
                             const int* __restrict__ adjc,
                             const float* __restrict__ dis,
                             const u16* __restrict__ y1,
                             u16* __restrict__ y2) {
    int tid = blockIdx.x * blockDim.x + threadIdx.x;
    int w = tid >> 6, l = tid & 63;
    int n = 2 * w + (l >> 5);
    int sg = (l >> 3) & 3;
    int ho = l & 7;
    int2 be = rowbe[n];
    float a[8] = {0.f, 0.f, 0.f, 0.f, 0.f, 0.f, 0.f, 0.f};
    #pragma unroll 2
    for (int j = be.x; j < be.y; j += 16) {
        int4 c = *(const int4*)&adjc[j + sg * 4];
        us8 v0 = *(const us8*)&y1[c.x * D + ho * 8];
        us8 v1 = *(const us8*)&y1[c.y * D + ho * 8];
        us8 v2 = *(const us8*)&y1[c.z * D + ho * 8];
        us8 v3 = *(const us8*)&y1[c.w * D + ho * 8];
        #pragma unroll
        for (int k = 0; k < 8; ++k)
            a[k] += (bf2f(v0[k]) + bf2f(v1[k])) + (bf2f(v2[k]) + bf2f(v3[k]));
    }
    #pragma unroll
    for (int k = 0; k < 8; ++k) {
        a[k] += __shfl_xor(a[k], 8);
        a[k] += __shfl_xor(a[k], 16);
    }
    if ((l & 31) < 8) {
        us8 s = *(const us8*)&y1[n * D + ho * 8];   // self loop
        float di = dis[n], d2 = di * di;
        us8 o;
        #pragma unroll
        for (int k = 0; k < 8; ++k) o[k] = f2bf(d2 * (a[k] + bf2f(s[k])));
        *(us8*)&y2[n * D + ho * 8] = o;
    }
}

// out = dsi*(w0*y1[n] + w1*y2[n]) + w2*di*(y2[n] + sum_c y2[c])
// (x reconstructed as dsi*y1[n] — no fp32 x stream.)
__global__ void prop2_kernel(const int2* __restrict__ rowbe,
                             const int* __restrict__ adjc,
                             const float* __restrict__ dis,
                             const float* __restrict__ dsi,
                             const u16* __restrict__ y1,
                             const u16* __restrict__ y2,
                             const float* __restrict__ wsm,
                             float* __restrict__ out) {
    int tid = blockIdx.x * blockDim.x + threadIdx.x;
    int w = tid >> 6, l = tid & 63;
    int n = 2 * w + (l >> 5);
    int sg = (l >> 3) & 3;
    int ho = l & 7;
    int2 be = rowbe[n];
    float a[8] = {0.f, 0.f, 0.f, 0.f, 0.f, 0.f, 0.f, 0.f};
    #pragma unroll 2
    for (int j = be.x; j < be.y; j += 16) {
        int4 c = *(const int4*)&adjc[j + sg * 4];
        us8 v0 = *(const us8*)&y2[c.x * D + ho * 8];
        us8 v1 = *(const us8*)&y2[c.y * D + ho * 8];
        us8 v2 = *(const us8*)&y2[c.z * D + ho * 8];
        us8 v3 = *(const us8*)&y2[c.w * D + ho * 8];
        #pragma unroll
        for (int k = 0; k < 8; ++k)
            a[k] += (bf2f(v0[k]) + bf2f(v1[k])) + (bf2f(v2[k]) + bf2f(v3[k]));
    }
    #pragma unroll
    for (int k = 0; k < 8; ++k) {
        a[k] += __shfl_xor(a[k], 8);
        a[k] += __shfl_xor(a[k], 16);
    }
    if ((l & 31) < 8) {
        us8 s1 = *(const us8*)&y1[n * D + ho * 8];
        us8 s2 = *(const us8*)&y2[n * D + ho * 8];
        float di = dis[n], ds = dsi[n];
        float w0 = wsm[0], w1 = wsm[1], w2 = wsm[2];
        float o[8];
        #pragma unroll
        for (int k = 0; k < 8; ++k) {
            float y2k = bf2f(s2[k]);
            o[k] = ds * (w0 * bf2f(s1[k]) + w1 * y2k) + w2 * (di * (a[k] + y2k));
        }
        float4 o0 = {o[0], o[1], o[2], o[3]};
        float4 o1 = {o[4], o[5], o[6], o[7]};
        *(float4*)&out[n * D + ho * 8] = o0;
        *(float4*)&out[n * D + ho * 8 + 4] = o1;
    }
}

// ---------------- launch ----------------

extern "C" void kernel_launch(void* const* d_in, const int* in_sizes, int n_in,
                              void* d_out, int out_size, void* d_ws, size_t ws_size,
                              hipStream_t stream) {
    const float* x   = (const float*)d_in[0];
    const int*   ei  = (const int*)d_in[1];   // [2, NE]
    const float* hw  = (const float*)d_in[2]; // [3]
    float*       out = (float*)d_out;

    const int* row = ei;       // scatter destination
    const int* col = ei + NE;  // gather source

    char* ws = (char*)d_ws;
    size_t off = 0;
    auto alloc = [&](size_t bytes) { size_t p = off; off += (bytes + 255) & ~(size_t)255; return p; };
    float* wsm    = (float*)(ws + alloc(16));
    int*   bcnt   = (int*)  (ws + alloc((size_t)BKT * 4));
    int*   bcnt2  = (int*)  (ws + alloc((size_t)BKT * 4));
    float* dis    = (float*)(ws + alloc((size_t)NN * 4));
    float* dsi    = (float*)(ws + alloc((size_t)NN * 4));
    u32*   buck   = (u32*)  (ws + alloc((size_t)BKT * CAP * 4));
    u16*   buck2  = (u16*)  (ws + alloc((size_t)BKT * CAP * 2));
    int*   adjc   = (int*)  (ws + alloc((size_t)BKT * PADCAP * 4));
    int2*  rowbe  = (int2*) (ws + alloc((size_t)NN * 8));
    u16*   y1     = (u16*)  (ws + alloc((size_t)(NN + 1) * D * 2));
    u16*   y2     = (u16*)  (ws + alloc((size_t)(NN + 1) * D * 2));

    setup_kernel<<<1, 1024, 0, stream>>>(hw, wsm, bcnt, bcnt2);
    fused_p1<<<P1_NB, P1_T, 0, stream>>>(row, col, bcnt, bcnt2, buck, buck2);
    deg_scale<<<BKT, 1024, 0, stream>>>(bcnt2, buck2, dis, dsi,
                                        (const float4*)x, (ushort4*)y1, (ushort4*)y2);
    p2_build<<<BKT, 1024, 0, stream>>>(bcnt, buck, adjc, rowbe);

    // 2 nodes per wave: NN/2 waves; 4 waves per 256-thread block.
    const int prop_blocks = (NN / 2 + 3) / 4; // 12500
    prop1_kernel<<<prop_blocks, 256, 0, stream>>>(rowbe, adjc, dis, y1, y2);
    prop2_kernel<<<prop_blocks, 256, 0, stream>>>(rowbe, adjc, dis, dsi, y1, y2, wsm, out);
}